// Round 9
// baseline (578.927 us; speedup 1.0000x reference)
//
#include <hip/hip_runtime.h>
#include <stdint.h>

#define NEG_SLOPE 0.2f
#define BN_EPS 1e-5f

typedef unsigned short u16;
typedef unsigned int   u32;
typedef __attribute__((ext_vector_type(2))) float  v2f;
typedef __attribute__((ext_vector_type(4))) float  f32x4;
typedef __attribute__((ext_vector_type(8))) short  short8;

__device__ __forceinline__ float lrelu(float x){ return fmaxf(x, NEG_SLOPE*x); }
__device__ __forceinline__ float bf2f(u16 u){ return __uint_as_float(((u32)u) << 16); }
__device__ __forceinline__ u16 f2bf(float f){           // round-to-nearest-even
  u32 u = __float_as_uint(f);
  return (u16)((u + 0x7fffu + ((u >> 16) & 1u)) >> 16);
}

// ---------------- build phase ----------------
__global__ __launch_bounds__(256) void init_k(int* __restrict__ counts, u16* __restrict__ s0,
                                              u16* __restrict__ s1, u16* __restrict__ s2,
                                              int nc, int n0, int n1, int n2){
  int t = blockIdx.x*256 + threadIdx.x;
  int y = blockIdx.y;
  if (y==0){ if (t<nc) counts[t]=0; }
  else {
    u16* sd = (y==1)?s0:(y==2)?s1:s2;
    int n   = (y==1)?n0:(y==2)?n1:n2;
    if (t<n) sd[t]=0xFFFFu;
  }
}

__global__ __launch_bounds__(256) void hist_all_k(const int* __restrict__ el0, const int* __restrict__ el1,
                                                  const int* __restrict__ el2, int* __restrict__ c0,
                                                  int* __restrict__ c1, int* __restrict__ c2,
                                                  int n0, int n1, int n2){
  int t = blockIdx.x*256 + threadIdx.x;
  int L = blockIdx.y;
  const int* dst = (L==0)?(el0+n0):(L==1)?(el1+n1):(el2+n2);
  int* counts    = (L==0)?c0:(L==1)?c1:c2;
  int n          = (L==0)?n0:(L==1)?n1:n2;
  if (t < n) atomicAdd(&counts[dst[t]], 1);
}

// padded scan per layer: row len = (deg+4)&~3 = 4*ceil((deg+1)/4), self at slot 0
__global__ __launch_bounds__(1024) void scan_all_k(int* __restrict__ c0, int* __restrict__ c1, int* __restrict__ c2,
                         int* __restrict__ ip0, int* __restrict__ ip1, int* __restrict__ ip2,
                         int* __restrict__ cu0, int* __restrict__ cu1, int* __restrict__ cu2,
                         u16* __restrict__ sd0, u16* __restrict__ sd1, u16* __restrict__ sd2,
                         int n0, int n1, int n2){
  int L = blockIdx.x;
  const int* counts = (L==0)?c0:(L==1)?c1:c2;
  int* indptr2      = (L==0)?ip0:(L==1)?ip1:ip2;
  int* cursor       = (L==0)?cu0:(L==1)?cu1:cu2;
  u16* ell_src      = (L==0)?sd0:(L==1)?sd1:sd2;
  int n             = (L==0)?n0:(L==1)?n1:n2;
  __shared__ int part[1024];
  int tid = threadIdx.x;
  int base = tid*4;
  int v0=0,v1=0,v2=0,v3=0;
  if (base+0<n) v0 = (counts[base+0]+4)&~3;
  if (base+1<n) v1 = (counts[base+1]+4)&~3;
  if (base+2<n) v2 = (counts[base+2]+4)&~3;
  if (base+3<n) v3 = (counts[base+3]+4)&~3;
  part[tid] = v0+v1+v2+v3;
  __syncthreads();
  for (int off=1; off<1024; off<<=1){
    int t2 = (tid>=off)?part[tid-off]:0;
    __syncthreads();
    part[tid] += t2;
    __syncthreads();
  }
  int run = (tid>0)?part[tid-1]:0;
  if (base+0<n){ indptr2[base+0]=run; cursor[base+0]=run+1; ell_src[run]=(u16)(base+0); run+=v0; }
  if (base+1<n){ indptr2[base+1]=run; cursor[base+1]=run+1; ell_src[run]=(u16)(base+1); run+=v1; }
  if (base+2<n){ indptr2[base+2]=run; cursor[base+2]=run+1; ell_src[run]=(u16)(base+2); run+=v2; }
  if (base+3<n){ indptr2[base+3]=run; cursor[base+3]=run+1; ell_src[run]=(u16)(base+3); run+=v3; }
  if (tid==0) indptr2[n] = part[1023];
}

__global__ __launch_bounds__(256) void scatter_all_k(const int* __restrict__ el0, const int* __restrict__ el1,
                         const int* __restrict__ el2, int* __restrict__ cu0, int* __restrict__ cu1,
                         int* __restrict__ cu2, u16* __restrict__ sd0, u16* __restrict__ sd1,
                         u16* __restrict__ sd2, int n0, int n1, int n2){
  int t = blockIdx.x*256 + threadIdx.x;
  int L = blockIdx.y;
  const int* el = (L==0)?el0:(L==1)?el1:el2;
  int* cursor   = (L==0)?cu0:(L==1)?cu1:cu2;
  u16* ell_src  = (L==0)?sd0:(L==1)?sd1:sd2;
  int n         = (L==0)?n0:(L==1)?n1:n2;
  if (t < n){
    int dd = el[n + t];
    int p = atomicAdd(&cursor[dd], 1);
    ell_src[p] = (u16)el[t];
  }
}

// ---------------- layer-0 GEMM (transposed out): h[n][b][f] ----------------
// wave = 8 groups x 8 lanes; group g handles row r = (nbase+g)*256 + b.
__global__ __launch_bounds__(256) void gemm3_k(const float* __restrict__ x, const float* __restrict__ Wg,
                        const float* __restrict__ asrc, const float* __restrict__ adst,
                        u16* __restrict__ h, float* __restrict__ als, float* __restrict__ ald, int nunits)
{
  const int l = threadIdx.x & 63;
  const int g = l >> 3;
  const int o = l & 7;
  float W0[8], W1[8], W2[8];
  float vs0=0.f,vs1=0.f,vs2=0.f,vd0=0.f,vd1=0.f,vd2=0.f;
  #pragma unroll
  for (int j=0;j<8;j++){
    W0[j] = Wg[      o*8 + j];
    W1[j] = Wg[ 64 + o*8 + j];
    W2[j] = Wg[128 + o*8 + j];
    float as = asrc[o*8 + j], ad = adst[o*8 + j];
    vs0 = fmaf(W0[j], as, vs0); vs1 = fmaf(W1[j], as, vs1); vs2 = fmaf(W2[j], as, vs2);
    vd0 = fmaf(W0[j], ad, vd0); vd1 = fmaf(W1[j], ad, vd1); vd2 = fmaf(W2[j], ad, vd2);
  }
  #pragma unroll
  for (int off=1; off<8; off<<=1){
    vs0 += __shfl_xor(vs0,off); vs1 += __shfl_xor(vs1,off); vs2 += __shfl_xor(vs2,off);
    vd0 += __shfl_xor(vd0,off); vd1 += __shfl_xor(vd1,off); vd2 += __shfl_xor(vd2,off);
  }
  int wv = blockIdx.x*4 + (int)(threadIdx.x>>6);
  int stride = gridDim.x*4;
  for (int u = wv; u < nunits; u += stride){
    int b = u & 255;
    int n = ((u >> 8) << 3) + g;
    float x0 = x[(size_t)(b*4096 + n)*3 + 0];
    float x1 = x[(size_t)(b*4096 + n)*3 + 1];
    float x2 = x[(size_t)(b*4096 + n)*3 + 2];
    size_t r = (size_t)n*256 + b;
    u32 pk[4];
    #pragma unroll
    for (int j=0;j<8;j+=2){
      float a0 = fmaf(x0, W0[j],   fmaf(x1, W1[j],   x2*W2[j]));
      float a1 = fmaf(x0, W0[j+1], fmaf(x1, W1[j+1], x2*W2[j+1]));
      pk[j>>1] = (u32)f2bf(a0) | ((u32)f2bf(a1) << 16);
    }
    ((int4*)(h + (r << 6)))[o] = make_int4((int)pk[0],(int)pk[1],(int)pk[2],(int)pk[3]);
    if (o == 0){
      als[r] = fmaf(x2, vs2, fmaf(x1, vs1, x0*vs0));
      ald[r] = fmaf(x2, vd2, fmaf(x1, vd1, x0*vd0));
    }
  }
}

// ---------------- prep (layers 1/2): BN finish of prev layer + W' frags + als/ald B-tile ----------------
__global__ __launch_bounds__(128) void prep_w_k(const float* __restrict__ W, const float* __restrict__ asrc,
                        const float* __restrict__ adst, const float* __restrict__ scratch, float invN,
                        u16* __restrict__ wswz, float* __restrict__ cvec){
  __shared__ float mean_s[64], rstd_s[64], vs_s[64], vd_s[64], cv_s[64], acc[128];
  int t = threadIdx.x;
  float s = 0.f;
  #pragma unroll 8
  for (int b2=0;b2<256;b2++) s += scratch[b2*128 + t];
  acc[t] = s;
  __syncthreads();
  if (t < 64){
    float m = acc[t]*invN;
    float var = acc[64+t]*invN - m*m;
    mean_s[t] = m; rstd_s[t] = rsqrtf(var + BN_EPS);
  }
  __syncthreads();
  if (t < 64){
    float c = 0.f;
    for (int k=0;k<64;k++) c = fmaf(mean_s[k]*rstd_s[k], W[k*64+t], c);
    cv_s[t] = c; cvec[t] = c;
    float vs = 0.f, vd = 0.f;
    for (int col=0; col<64; col++){
      float wv = W[t*64+col];
      vs = fmaf(wv, asrc[col], vs);
      vd = fmaf(wv, adst[col], vd);
    }
    vs_s[t] = rstd_s[t]*vs; vd_s[t] = rstd_s[t]*vd;
  }
  __syncthreads();
  if (t == 0){
    float cs=0.f, cd=0.f;
    for (int col=0; col<64; col++){ cs = fmaf(cv_s[col], asrc[col], cs); cd = fmaf(cv_s[col], adst[col], cd); }
    cvec[64] = cs; cvec[65] = cd;
  }
  if (t < 64){
    #pragma unroll
    for (int f=0; f<8; f++){
      int tt = f >> 1, ch = f & 1;
      #pragma unroll
      for (int j=0; j<8; j++){
        int k   = ch*32 + (t>>4)*8 + j;
        int col = tt*16 + (t&15);
        wswz[(f*64 + t)*8 + j] = f2bf(rstd_s[k] * W[k*64 + col]);
      }
    }
    #pragma unroll
    for (int f=8; f<10; f++){
      int ch = f - 8;
      #pragma unroll
      for (int j=0; j<8; j++){
        int k = ch*32 + (t>>4)*8 + j;
        int colp = t & 15;
        float val = (colp==0)? vs_s[k] : (colp==1)? vd_s[k] : 0.f;
        wswz[(f*64 + t)*8 + j] = f2bf(val);
      }
    }
  }
}

// ---------------- layers 1/2 GEMM via MFMA (row-order agnostic) ----------------
__global__ __launch_bounds__(256) void gemm64_mfma_k(const u16* __restrict__ Pin, const u16* __restrict__ wswz,
                        const float* __restrict__ cvec,
                        u16* __restrict__ h, float* __restrict__ als, float* __restrict__ ald, int nblk16)
{
  const int l = threadIdx.x & 63;
  const int q = l >> 4;
  const int c = l & 15;
  short8 B[10];
  const int4* wsw = (const int4*)wswz;
  #pragma unroll
  for (int f=0; f<10; f++){
    int4 v = wsw[f*64 + l];
    B[f] = *(short8*)&v;
  }
  float cl[4];
  #pragma unroll
  for (int t=0;t<4;t++) cl[t] = cvec[t*16+c];
  const float const_s = cvec[64], const_d = cvec[65];
  int gw = blockIdx.x*4 + (int)(threadIdx.x>>6);
  int stride = gridDim.x*4;
  for (int blk = gw; blk < nblk16; blk += stride){
    size_t rowbase = (size_t)blk*16;
    const int4* arow = (const int4*)(Pin + (rowbase + c)*64);
    int4 a0v = arow[q];
    int4 a1v = arow[4+q];
    short8 A0 = *(short8*)&a0v, A1 = *(short8*)&a1v;
    f32x4 C0={0.f,0.f,0.f,0.f}, C1=C0, C2=C0, C3=C0, C4=C0;
    C0 = __builtin_amdgcn_mfma_f32_16x16x32_bf16(A0, B[0], C0, 0,0,0);
    C0 = __builtin_amdgcn_mfma_f32_16x16x32_bf16(A1, B[1], C0, 0,0,0);
    C1 = __builtin_amdgcn_mfma_f32_16x16x32_bf16(A0, B[2], C1, 0,0,0);
    C1 = __builtin_amdgcn_mfma_f32_16x16x32_bf16(A1, B[3], C1, 0,0,0);
    C2 = __builtin_amdgcn_mfma_f32_16x16x32_bf16(A0, B[4], C2, 0,0,0);
    C2 = __builtin_amdgcn_mfma_f32_16x16x32_bf16(A1, B[5], C2, 0,0,0);
    C3 = __builtin_amdgcn_mfma_f32_16x16x32_bf16(A0, B[6], C3, 0,0,0);
    C3 = __builtin_amdgcn_mfma_f32_16x16x32_bf16(A1, B[7], C3, 0,0,0);
    C4 = __builtin_amdgcn_mfma_f32_16x16x32_bf16(A0, B[8], C4, 0,0,0);
    C4 = __builtin_amdgcn_mfma_f32_16x16x32_bf16(A1, B[9], C4, 0,0,0);
    #pragma unroll
    for (int t=0;t<4;t++){
      f32x4 C = (t==0)?C0:(t==1)?C1:(t==2)?C2:C3;
      #pragma unroll
      for (int reg=0;reg<4;reg++){
        h[(rowbase + q*4 + reg)*64 + t*16 + c] = f2bf(C[reg] - cl[t]);
      }
    }
    if (c == 0){
      #pragma unroll
      for (int reg=0;reg<4;reg++) als[rowbase + q*4 + reg] = C4[reg] - const_s;
    } else if (c == 1){
      #pragma unroll
      for (int reg=0;reg<4;reg++) ald[rowbase + q*4 + reg] = C4[reg] - const_d;
    }
  }
}

// ---------------- GAT gather (transposed, batch-dense) + softmax + bias + relu + pool ----------------
// h layout: [n][b(256)][f(64)] bf16. Wave = 8 graphs (b-chunk slice) x 8 feat-octets.
// One wave handles one pool PAIR for its 8 graphs; both dests sequentially, then max.
// chunk c in [0,32): b-slice c*8..c*8+7. c&7 == bid&7 -> chunk pinned to one XCD's L2.
__global__ __launch_bounds__(256) void gat_pool_k(const u16* __restrict__ h, const float* __restrict__ bias,
                      const int* __restrict__ indptr2, const int* __restrict__ counts,
                      const u16* __restrict__ ell_src,
                      const float* __restrict__ als, const float* __restrict__ ald,
                      u16* __restrict__ P, int log2NS)
{
  const int l = threadIdx.x & 63;
  const int b_off = l >> 3;
  const int o = l & 7;
  const int wv = threadIdx.x >> 6;
  const int bid = blockIdx.x;
  const int log2bpc = log2NS - 3;                 // blocks per chunk = npairs/4
  const int c = (bid & 7) | (((bid >> (3 + log2bpc)) & 3) << 3);
  const int within = (bid >> 3) & ((1 << log2bpc) - 1);
  const int pair = within*4 + wv;
  const int bg = c*8 + b_off;
  const int laneoff = bg*64 + o*8;                // elems within an s-tile (32 KB)
  const int nmask = (1 << log2NS) - 1;

  float q[8];
  #pragma unroll
  for (int j=0;j<8;j++) q[j] = 0.f;

  #pragma unroll
  for (int dd=0; dd<2; dd++){
    const int d = 2*pair + dd;
    const int p0 = indptr2[d];
    const int cnt = counts[d] + 1;                // exact: self + deg (wave-uniform)
    const float ald_d = ald[(size_t)d*256 + bg];

    v2f a01={0.f,0.f}, a23={0.f,0.f}, a45={0.f,0.f}, a67={0.f,0.f};
    float z = 0.f;

    // A/B staged, loads 2 items ahead, no register shifting
    int mA = ell_src[p0] & nmask;
    int4 hA = *(const int4*)(h + (((size_t)mA) << 14) + laneoff);
    float aA = als[(size_t)mA*256 + bg];
    int mB = ell_src[p0+1] & nmask;
    int4 hB = *(const int4*)(h + (((size_t)mB) << 14) + laneoff);
    float aB = als[(size_t)mB*256 + bg];

    int it = 0;
    while (it + 1 < cnt){
      // consume A (item it)
      {
        float w = __expf(lrelu(aA + ald_d));
        z += w;
        v2f w2 = {w, w};
        u32 r0=((u32*)&hA)[0], r1=((u32*)&hA)[1], r2=((u32*)&hA)[2], r3=((u32*)&hA)[3];
        a01 += (v2f){ __uint_as_float(r0 << 16), __uint_as_float(r0 & 0xffff0000u) } * w2;
        a23 += (v2f){ __uint_as_float(r1 << 16), __uint_as_float(r1 & 0xffff0000u) } * w2;
        a45 += (v2f){ __uint_as_float(r2 << 16), __uint_as_float(r2 & 0xffff0000u) } * w2;
        a67 += (v2f){ __uint_as_float(r3 << 16), __uint_as_float(r3 & 0xffff0000u) } * w2;
      }
      // reload A with item it+2 (pad slots masked; never consumed)
      mA = ell_src[p0 + it + 2] & nmask;
      hA = *(const int4*)(h + (((size_t)mA) << 14) + laneoff);
      aA = als[(size_t)mA*256 + bg];
      // consume B (item it+1)
      {
        float w = __expf(lrelu(aB + ald_d));
        z += w;
        v2f w2 = {w, w};
        u32 r0=((u32*)&hB)[0], r1=((u32*)&hB)[1], r2=((u32*)&hB)[2], r3=((u32*)&hB)[3];
        a01 += (v2f){ __uint_as_float(r0 << 16), __uint_as_float(r0 & 0xffff0000u) } * w2;
        a23 += (v2f){ __uint_as_float(r1 << 16), __uint_as_float(r1 & 0xffff0000u) } * w2;
        a45 += (v2f){ __uint_as_float(r2 << 16), __uint_as_float(r2 & 0xffff0000u) } * w2;
        a67 += (v2f){ __uint_as_float(r3 << 16), __uint_as_float(r3 & 0xffff0000u) } * w2;
      }
      // reload B with item it+3
      mB = ell_src[p0 + it + 3] & nmask;
      hB = *(const int4*)(h + (((size_t)mB) << 14) + laneoff);
      aB = als[(size_t)mB*256 + bg];
      it += 2;
    }
    if (it < cnt){  // tail (odd cnt): consume A
      float w = __expf(lrelu(aA + ald_d));
      z += w;
      v2f w2 = {w, w};
      u32 r0=((u32*)&hA)[0], r1=((u32*)&hA)[1], r2=((u32*)&hA)[2], r3=((u32*)&hA)[3];
      a01 += (v2f){ __uint_as_float(r0 << 16), __uint_as_float(r0 & 0xffff0000u) } * w2;
      a23 += (v2f){ __uint_as_float(r1 << 16), __uint_as_float(r1 & 0xffff0000u) } * w2;
      a45 += (v2f){ __uint_as_float(r2 << 16), __uint_as_float(r2 & 0xffff0000u) } * w2;
      a67 += (v2f){ __uint_as_float(r3 << 16), __uint_as_float(r3 & 0xffff0000u) } * w2;
    }

    float rz = __builtin_amdgcn_rcpf(z);
    const float* bp = bias + o*8;
    q[0] = fmaxf(q[0], fmaxf(fmaf(a01.x, rz, bp[0]), 0.f));
    q[1] = fmaxf(q[1], fmaxf(fmaf(a01.y, rz, bp[1]), 0.f));
    q[2] = fmaxf(q[2], fmaxf(fmaf(a23.x, rz, bp[2]), 0.f));
    q[3] = fmaxf(q[3], fmaxf(fmaf(a23.y, rz, bp[3]), 0.f));
    q[4] = fmaxf(q[4], fmaxf(fmaf(a45.x, rz, bp[4]), 0.f));
    q[5] = fmaxf(q[5], fmaxf(fmaf(a45.y, rz, bp[5]), 0.f));
    q[6] = fmaxf(q[6], fmaxf(fmaf(a67.x, rz, bp[6]), 0.f));
    q[7] = fmaxf(q[7], fmaxf(fmaf(a67.y, rz, bp[7]), 0.f));
  }

  u32 w0 = (u32)f2bf(q[0]) | ((u32)f2bf(q[1]) << 16);
  u32 w1 = (u32)f2bf(q[2]) | ((u32)f2bf(q[3]) << 16);
  u32 w2p = (u32)f2bf(q[4]) | ((u32)f2bf(q[5]) << 16);
  u32 w3 = (u32)f2bf(q[6]) | ((u32)f2bf(q[7]) << 16);
  // pooled row (pair) in same transposed layout: P[(pair*256 + bg)*64 + f]
  ((int4*)(P + (((size_t)pair*256 + bg) << 6)))[o] = make_int4((int)w0,(int)w1,(int)w2p,(int)w3);
}

// ---------------- BatchNorm stats (stage 1) ----------------
__global__ __launch_bounds__(256) void bn_stats_k(const u16* __restrict__ P, float* __restrict__ scratch, int iters){
  const int l = threadIdx.x & 63;
  int gw = blockIdx.x*4 + (threadIdx.x>>6);
  int GW = gridDim.x*4;
  float s = 0.f, s2 = 0.f;
  #pragma unroll 4
  for (int i = 0; i < iters; i++){
    int r = gw + i*GW;
    float v = bf2f(P[(size_t)r*64 + l]);
    s += v; s2 = fmaf(v, v, s2);
  }
  __shared__ float ls[256], ls2[256];
  ls[threadIdx.x] = s; ls2[threadIdx.x] = s2;
  __syncthreads();
  if (threadIdx.x < 64){
    float S  = ls[threadIdx.x] + ls[threadIdx.x+64] + ls[threadIdx.x+128] + ls[threadIdx.x+192];
    float S2 = ls2[threadIdx.x] + ls2[threadIdx.x+64] + ls2[threadIdx.x+128] + ls2[threadIdx.x+192];
    scratch[blockIdx.x*128 + threadIdx.x] = S;
    scratch[blockIdx.x*128 + 64 + threadIdx.x] = S2;
  }
}

__global__ __launch_bounds__(128) void bn_finish_k(const float* __restrict__ scratch, float* __restrict__ stats,
                                                   int nblocks, float invN){
  __shared__ float accs[128];
  int j = threadIdx.x;
  float s = 0.f;
  #pragma unroll 8
  for (int b=0;b<nblocks;b++) s += scratch[b*128 + j];
  accs[j] = s;
  __syncthreads();
  if (j < 64){
    float m = accs[j]*invN;
    float var = accs[j+64]*invN - m*m;
    stats[j] = m;
    stats[64+j] = rsqrtf(var + BN_EPS);
  }
}

// ---------------- final BN apply + transpose back: P[n][b][f] bf16 -> out[b][n][f] f32 ----------------
__global__ __launch_bounds__(256) void bn_apply_k(const u16* __restrict__ P, const float* __restrict__ stats,
                                                  float* __restrict__ out, int nunits){
  int u = blockIdx.x*4 + (int)(threadIdx.x>>6);
  if (u >= nunits) return;
  const int l = threadIdx.x & 63;
  const int b_off = l >> 3;
  const int o = l & 7;
  int c = u & 31, n = u >> 5;
  int bg = c*8 + b_off;
  int4 v = *(const int4*)(P + (((size_t)n*256 + bg) << 6) + o*8);
  u32 r0=((u32*)&v)[0], r1=((u32*)&v)[1], r2=((u32*)&v)[2], r3=((u32*)&v)[3];
  const float* mp = stats + o*8;
  const float* rp = stats + 64 + o*8;
  float4 f0, f1;
  f0.x = (__uint_as_float(r0 << 16)          - mp[0]) * rp[0];
  f0.y = (__uint_as_float(r0 & 0xffff0000u)  - mp[1]) * rp[1];
  f0.z = (__uint_as_float(r1 << 16)          - mp[2]) * rp[2];
  f0.w = (__uint_as_float(r1 & 0xffff0000u)  - mp[3]) * rp[3];
  f1.x = (__uint_as_float(r2 << 16)          - mp[4]) * rp[4];
  f1.y = (__uint_as_float(r2 & 0xffff0000u)  - mp[5]) * rp[5];
  f1.z = (__uint_as_float(r3 << 16)          - mp[6]) * rp[6];
  f1.w = (__uint_as_float(r3 & 0xffff0000u)  - mp[7]) * rp[7];
  float* op = out + (size_t)bg*32768 + (size_t)n*64 + o*8;
  *(float4*)(op)   = f0;
  *(float4*)(op+4) = f1;
}

// ---------------- launcher ----------------
extern "C" void kernel_launch(void* const* d_in, const int* in_sizes, int n_in,
                              void* d_out, int out_size, void* d_ws, size_t ws_size,
                              hipStream_t stream)
{
  const float* x      = (const float*)d_in[0];
  const float* Wl[3]  = {(const float*)d_in[1], (const float*)d_in[7],  (const float*)d_in[13]};
  const float* asl[3] = {(const float*)d_in[2], (const float*)d_in[8],  (const float*)d_in[14]};
  const float* adl[3] = {(const float*)d_in[3], (const float*)d_in[9],  (const float*)d_in[15]};
  const float* bl[3]  = {(const float*)d_in[4], (const float*)d_in[10], (const float*)d_in[16]};
  const int*   el[3]  = {(const int*)d_in[5],   (const int*)d_in[11],   (const int*)d_in[17]};

  const int NS[4]  = {4096, 2048, 1024, 512};
  const int EPB[3] = {32768, 16384, 8192};
  const int LOG2NS[3] = {12, 11, 10};
  const int ECAP[3] = {32768+4*4096, 16384+4*2048, 8192+4*1024};  // 49152, 24576, 12288
  const int BATCH = 256;

  char* ws = (char*)d_ws;
  size_t off = 0;
  auto alloc = [&](size_t bytes)->char*{
    char* p = ws + off; off += (bytes + 255) & ~(size_t)255; return p;
  };

  u16*   hbuf    = (u16*)alloc((size_t)BATCH*NS[0]*64*2);            // 128 MB  [n][b][f]
  u16*   Pbuf    = (u16*)alloc((size_t)BATCH*NS[1]*64*2);            //  64 MB  [pn][b][f]
  float* als     = (float*)alloc((size_t)BATCH*NS[0]*4);             //   4 MB  [n][b]
  float* ald     = (float*)alloc((size_t)BATCH*NS[0]*4);             //   4 MB
  float* scratch = (float*)alloc(256*128*4);
  float* stats   = (float*)alloc(128*4);
  u16*   wswz    = (u16*)alloc(10*64*8*2);
  float* cvec    = (float*)alloc(128*4);
  int* counts_all = (int*)alloc((size_t)(NS[0]+NS[1]+NS[2])*4);
  int* cursor_all = (int*)alloc((size_t)(NS[0]+NS[1]+NS[2])*4);
  int *counts[3], *cursor[3], *indptr2[3];
  u16* ell_src[3];
  counts[0]=counts_all; counts[1]=counts_all+NS[0]; counts[2]=counts_all+NS[0]+NS[1];
  cursor[0]=cursor_all; cursor[1]=cursor_all+NS[0]; cursor[2]=cursor_all+NS[0]+NS[1];
  for (int i=0;i<3;i++){
    indptr2[i] = (int*)alloc((size_t)(NS[i]+1)*4);
    ell_src[i] = (u16*)alloc((size_t)(ECAP[i]+16)*2);
  }
  if (off > ws_size) return;

  // ---- build ----
  int ctot = NS[0]+NS[1]+NS[2];
  {
    dim3 ginit((ECAP[0]+16+255)/256, 4);
    init_k<<<ginit, 256, 0, stream>>>(counts_all, ell_src[0], ell_src[1], ell_src[2],
                                      ctot, ECAP[0]+16, ECAP[1]+16, ECAP[2]+16);
    dim3 ghist(EPB[0]/256, 3);
    hist_all_k<<<ghist, 256, 0, stream>>>(el[0], el[1], el[2], counts[0], counts[1], counts[2],
                                          EPB[0], EPB[1], EPB[2]);
    scan_all_k<<<3, 1024, 0, stream>>>(counts[0], counts[1], counts[2],
                                       indptr2[0], indptr2[1], indptr2[2],
                                       cursor[0], cursor[1], cursor[2],
                                       ell_src[0], ell_src[1], ell_src[2],
                                       NS[0], NS[1], NS[2]);
    scatter_all_k<<<ghist, 256, 0, stream>>>(el[0], el[1], el[2],
                                             cursor[0], cursor[1], cursor[2],
                                             ell_src[0], ell_src[1], ell_src[2],
                                             EPB[0], EPB[1], EPB[2]);
  }

  // ---- layers ----
  for (int i=0;i<3;i++){
    int ntot = BATCH*NS[i];

    if (i==0){
      gemm3_k<<<1024, 256, 0, stream>>>(x, Wl[0], asl[0], adl[0], hbuf, als, ald, ntot/8);
    } else {
      float invN = 1.0f / (float)(BATCH*NS[i]);
      prep_w_k<<<1, 128, 0, stream>>>(Wl[i], asl[i], adl[i], scratch, invN, wswz, cvec);
      gemm64_mfma_k<<<2048, 256, 0, stream>>>(Pbuf, wswz, cvec, hbuf, als, ald, ntot/16);
    }

    // gather: 32 chunks x (npairs/4 blocks); chunk c pinned to XCD (c&7 == bid&7)
    int nblocks = 4 * NS[i];                       // 32 * (NS/2/4)
    gat_pool_k<<<nblocks, 256, 0, stream>>>(hbuf, bl[i], indptr2[i], counts[i],
                                            ell_src[i], als, ald, Pbuf, LOG2NS[i]);

    bn_stats_k<<<256, 256, 0, stream>>>(Pbuf, scratch, (ntot/2)/1024);
  }

  // final BN: finish stats of layer 2, then transpose-materialize into d_out
  bn_finish_k<<<1, 128, 0, stream>>>(scratch, stats, 256, 1.0f/(float)(BATCH*NS[3]));
  int nunits = NS[3]*32;                           // 512 nodes x 32 b-chunks
  bn_apply_k<<<nunits/4, 256, 0, stream>>>(Pbuf, stats, (float*)d_out, nunits);
}